// Round 3
// baseline (757.732 us; speedup 1.0000x reference)
//
#include <hip/hip_runtime.h>
#include <math.h>

#define B_  2
#define N_  384
#define C_  256
#define H_  4
#define D_  64
#define NBH (B_*H_)            // 8
#define TSZ (NBH*N_*D_)        // 196608 floats per projected tensor [bh][n][d]
#define ESZ (NBH*N_*N_)        // 1179648 elems per logit matrix [bh][i][j]
#define SCALE 0.125f           // D^-0.5
#define PIT 72                 // padded LDS pitch in f16 (144B) -> 2-way max bank alias
#define NWSLICE (NBH*N_*68)    // 208896 floats per numw partial

typedef _Float16 f16;
typedef f16  f16x8 __attribute__((ext_vector_type(8)));
typedef f16  f16x4 __attribute__((ext_vector_type(4)));
typedef float f32x4 __attribute__((ext_vector_type(4)));

// ---------------------------------------------------------------------------
// Kernel 1: projection (unchanged). proj[t][bh][n][d], t in {a,b,c,v1,v2}, f32.
// ---------------------------------------------------------------------------
__global__ __launch_bounds__(256) void proj_kernel(const float* __restrict__ x,
                                                   const float* __restrict__ W,
                                                   float* __restrict__ proj) {
    __shared__ float Xs[32][68];
    __shared__ float Ws[32][68];
    const int tid = threadIdx.x;
    const int tx = tid & 15, ty = tid >> 4;
    const int m0 = blockIdx.x * 64;
    const int c0 = blockIdx.y * 64;
    const int t  = c0 >> 8;
    const int wbase = ((t >= 3) ? (t + 3) : t) * 256;

    float acc[4][4] = {{0.f}};
    for (int k0 = 0; k0 < 256; k0 += 32) {
        __syncthreads();
#pragma unroll
        for (int l = 0; l < 8; ++l) {
            const int idx = l * 256 + tid;
            const int mi = idx >> 5, kk = idx & 31;
            Xs[kk][mi] = x[(m0 + mi) * 256 + k0 + kk];
            const int rem = (c0 + mi) & 255;
            Ws[kk][mi] = W[(wbase + rem) * 256 + k0 + kk];
        }
        __syncthreads();
#pragma unroll
        for (int kk = 0; kk < 32; ++kk) {
            const float4 xf = *(const float4*)&Xs[kk][ty * 4];
            const float4 wf = *(const float4*)&Ws[kk][tx * 4];
            const float xa[4] = {xf.x, xf.y, xf.z, xf.w};
            const float wa[4] = {wf.x, wf.y, wf.z, wf.w};
#pragma unroll
            for (int q = 0; q < 4; ++q)
#pragma unroll
                for (int p = 0; p < 4; ++p)
                    acc[q][p] += xa[q] * wa[p];
        }
    }
#pragma unroll
    for (int q = 0; q < 4; ++q) {
        const int r = m0 + ty * 4 + q;
        const int b = r / N_;
        const int n = r - b * N_;
#pragma unroll
        for (int p = 0; p < 4; ++p) {
            const int rem = (c0 + tx * 4 + p) & 255;
            const int h = rem >> 6, d = rem & 63;
            proj[t * TSZ + ((b * H_ + h) * N_ + n) * D_ + d] = acc[q][p];
        }
    }
}

// ---------------------------------------------------------------------------
// Kernel 2: exp-logit matrices, mixed-dtype outputs (unchanged).
// ---------------------------------------------------------------------------
__global__ __launch_bounds__(256) void logits_kernel(const float* __restrict__ proj,
                                                     f16* __restrict__ eabt16,
                                                     float* __restrict__ ecd,
                                                     f16* __restrict__ eef16) {
    __shared__ float Xs[32][68];
    __shared__ float Ys[32][68];
    const int tid = threadIdx.x;
    const int tx = tid & 15, ty = tid >> 4;
    const int i0 = blockIdx.x * 64, j0 = blockIdx.y * 64;
    const int q  = blockIdx.z >> 3;
    const int bh = blockIdx.z & 7;
    const int xt = q;
    const int yt = (q == 2) ? 0 : (q + 1);
    const float* Xp = proj + xt * TSZ + bh * N_ * D_;
    const float* Yp = proj + yt * TSZ + bh * N_ * D_;

    float acc[4][4] = {{0.f}};
    for (int k0 = 0; k0 < 64; k0 += 32) {
        __syncthreads();
#pragma unroll
        for (int l = 0; l < 8; ++l) {
            const int idx = l * 256 + tid;
            const int mi = idx >> 5, kk = idx & 31;
            Xs[kk][mi] = Xp[(i0 + mi) * 64 + k0 + kk];
            Ys[kk][mi] = Yp[(j0 + mi) * 64 + k0 + kk];
        }
        __syncthreads();
#pragma unroll
        for (int kk = 0; kk < 32; ++kk) {
            const float4 xf = *(const float4*)&Xs[kk][ty * 4];
            const float4 yf = *(const float4*)&Ys[kk][tx * 4];
            const float xa[4] = {xf.x, xf.y, xf.z, xf.w};
            const float ya[4] = {yf.x, yf.y, yf.z, yf.w};
#pragma unroll
            for (int qq = 0; qq < 4; ++qq)
#pragma unroll
                for (int p = 0; p < 4; ++p)
                    acc[qq][p] += xa[qq] * ya[p];
        }
    }
#pragma unroll
    for (int qq = 0; qq < 4; ++qq)
#pragma unroll
        for (int p = 0; p < 4; ++p) {
            const float e = expf(acc[qq][p] * SCALE);
            const int ii = i0 + ty * 4 + qq;
            const int jj = j0 + tx * 4 + p;
            if (q == 0)      eabt16[(size_t)bh * N_ * N_ + jj * N_ + ii] = (f16)e;
            else if (q == 1) ecd   [(size_t)bh * N_ * N_ + ii * N_ + jj] = e;
            else             eef16 [(size_t)bh * N_ * N_ + ii * N_ + jj] = (f16)e;
        }
}

// ---------------------------------------------------------------------------
// Kernel 3 (dominant), MFMA f16.
// Round-3 changes vs round-0 (the 177 us reference):
//  * LDS 62464 -> 52224 (us + es + v1s only) => 3 blocks/CU instead of 2.
//    - abts staging dropped: ab read directly from L2-resident eabt (8B
//      dwordx2 per tile; 4-wave redundancy absorbed by L1).
//    - v2k staging dropped: U-build reads v2 as transposed float4s
//      (v2[k][dg*4..+3] is 16B contiguous) -> one fewer barrier pair/kt.
//  * T14 async-stage on es: next jt's eEF tile loaded to regs during the
//    current jt's MFMA/fold; written to LDS after the barrier. L2 latency
//    leaves the barrier-to-barrier critical path.
//  * Hoisted zero f32x4 as MFMA C-in (kills 64 v_mov t-inits per jt).
//  * Keeps cooperative LDS U-build (96-VGPR-friendly; round-1/2's
//    register-built af cost 216 VGPRs) and the 2-way kt split.
// ---------------------------------------------------------------------------
__global__ __launch_bounds__(256) void triplet_mfma_kernel(
        const f16*  __restrict__ eabt,   // [bh][j][i]
        const float* __restrict__ ecd,   // [bh][i][k]
        const f16*  __restrict__ eef,    // [bh][j][k]
        const float* __restrict__ v1,    // [bh][n][64]
        const float* __restrict__ v2,    // [bh][n][64]
        float* __restrict__ num0,        // [bh][i][68] partial (kt 0..2)
        float* __restrict__ num1) {      // [bh][i][68] partial (kt 3..5)
    __shared__ __align__(16) unsigned char smem_raw[52224];
    f16*   us   = (f16*)smem_raw;                    // 4 * 64*PIT f16 = 36864 B
    f16*   es   = us + 4 * 64 * PIT;                 // 64*PIT f16     =  9216 B
    float* v1s  = (float*)(smem_raw + 46080);        // 384*4 f32      =  6144 B

    const int tid  = threadIdx.x;
    const int lane = tid & 63;
    const int w    = tid >> 6;        // wave id = d slot
    const int quad = lane >> 4;
    const int lr   = lane & 15;
    const int i0 = blockIdx.x * 64;
    const int dg = blockIdx.y;        // 0..16
    const int zz = blockIdx.z;
    const int bh    = zz & 7;
    const int split = zz >> 3;        // 0 or 1 -> kt half
    const int dd = dg * 4 + w;        // 0..67 (>=64: denominator)

    const f16*   eabtb = eabt + (size_t)bh * N_ * N_;
    const float* ecdb  = ecd  + (size_t)bh * N_ * N_;
    const f16*   eefb  = eef  + (size_t)bh * N_ * N_;
    const float* v1b   = v1 + (size_t)bh * N_ * D_;
    const float* v2b   = v2 + (size_t)bh * N_ * D_;
    float* numout = split ? num1 : num0;

    // stage v1 columns for the 4 d-slots: v1s[j*4 + c]
#pragma unroll
    for (int it = 0; it < 6; ++it) {
        const int id = it * 256 + tid;          // 0..1535
        const int j = id >> 2, c = id & 3;
        const int d2 = dg * 4 + c;
        v1s[id] = (d2 < 64) ? v1b[j * 64 + d2] : 1.0f;
    }

    float numacc[16];
#pragma unroll
    for (int r = 0; r < 16; ++r) numacc[r] = 0.f;

    const f32x4 zero4 = {0.f, 0.f, 0.f, 0.f};

    // U-build thread roles (fixed across kt)
    const int brow = tid >> 4;        // 0..15
    const int kcol = (tid & 15) * 4;  // 0..60
    // es staging roles
    const int srow = tid >> 3;        // 0..31
    const int sblk = tid & 7;         // 0..7

    const int ktbeg = split * 3;
    for (int kt = ktbeg; kt < ktbeg + 3; ++kt) {
        const int k0 = kt * 64;
        // v2 transposed loads for the U build (global, no LDS dep yet):
        // v2f[e].component(d) = v2[k0+kcol+e][dg*4+d]
        float4 v2f[4];
        if (dg < 16) {
#pragma unroll
            for (int e = 0; e < 4; ++e)
                v2f[e] = *(const float4*)&v2b[(k0 + kcol + e) * 64 + dg * 4];
        } else {
#pragma unroll
            for (int e = 0; e < 4; ++e)
                v2f[e] = make_float4(1.f, 1.f, 1.f, 1.f);
        }
        __syncthreads();                 // prior readers of us/es done
        // build U16[d][64i][PIT k] = f16(eCD * v2col)
#pragma unroll
        for (int it = 0; it < 4; ++it) {
            const int row = it * 16 + brow;
            const float4 c4 = *(const float4*)&ecdb[(i0 + row) * N_ + k0 + kcol];
#pragma unroll
            for (int d = 0; d < 4; ++d) {
                union { f16 h[4]; unsigned long long u; } pk;
                pk.h[0] = (f16)(c4.x * ((const float*)&v2f[0])[d]);
                pk.h[1] = (f16)(c4.y * ((const float*)&v2f[1])[d]);
                pk.h[2] = (f16)(c4.z * ((const float*)&v2f[2])[d]);
                pk.h[3] = (f16)(c4.w * ((const float*)&v2f[3])[d]);
                *(unsigned long long*)(us + d * 64 * PIT + row * PIT + kcol) = pk.u;
            }
        }
        __syncthreads();                 // us ready
        // A-frags for this wave's d, all 4 i-subtiles x 2 k-halves
        f16x8 af[4][2];
#pragma unroll
        for (int isub = 0; isub < 4; ++isub)
#pragma unroll
            for (int ks = 0; ks < 2; ++ks)
                af[isub][ks] = *(const f16x8*)(us + w * 64 * PIT +
                                               (isub * 16 + lr) * PIT + (ks * 4 + quad) * 8);

        // prefetch es tile for jt=0
        uint4 pf0 = *(const uint4*)(eefb + (srow) * N_ + k0 + sblk * 8);
        uint4 pf1 = *(const uint4*)(eefb + (32 + srow) * N_ + k0 + sblk * 8);

        for (int jt = 0; jt < 6; ++jt) {
            const int j0 = jt * 64;
            __syncthreads();             // prior readers of es done
            *(uint4*)(es + srow * PIT + sblk * 8)        = pf0;
            *(uint4*)(es + (32 + srow) * PIT + sblk * 8) = pf1;
            __syncthreads();
            if (jt < 5) {                // T14: issue next tile's loads now;
                pf0 = *(const uint4*)(eefb + (j0 + 64 + srow) * N_ + k0 + sblk * 8);
                pf1 = *(const uint4*)(eefb + (j0 + 96 + srow) * N_ + k0 + sblk * 8);
            }                            // latency hides under MFMA/fold below
            // MFMA + immediate fold of the partial R tile
#pragma unroll
            for (int js = 0; js < 4; ++js) {
                const f16x8 bf0 = *(const f16x8*)(es + (js * 16 + lr) * PIT + quad * 8);
                const f16x8 bf1 = *(const f16x8*)(es + (js * 16 + lr) * PIT + (4 + quad) * 8);
                const float v1v = v1s[(j0 + js * 16 + lr) * 4 + w];
                // ab straight from L2: row j0+js*16+lr, cols i0+quad*4+isub*16
                const f16* abp = eabtb + (j0 + js * 16 + lr) * N_ + i0 + quad * 4;
#pragma unroll
                for (int isub = 0; isub < 4; ++isub) {
                    f32x4 t;
                    t = __builtin_amdgcn_mfma_f32_16x16x32_f16(af[isub][0], bf0, zero4, 0, 0, 0);
                    t = __builtin_amdgcn_mfma_f32_16x16x32_f16(af[isub][1], bf1, t, 0, 0, 0);
                    const f16x4 ab = *(const f16x4*)(abp + isub * 16);
#pragma unroll
                    for (int q = 0; q < 4; ++q)
                        numacc[isub * 4 + q] += (float)ab[q] * (v1v * t[q]);
                }
            }
        }
    }
    // reduce the j-residues (low 4 lane bits) and write
#pragma unroll
    for (int r = 0; r < 16; ++r) {
        float v = numacc[r];
        v += __shfl_xor(v, 1);
        v += __shfl_xor(v, 2);
        v += __shfl_xor(v, 4);
        v += __shfl_xor(v, 8);
        numacc[r] = v;
    }
    if (lr == 0) {
#pragma unroll
        for (int r = 0; r < 16; ++r) {
            const int i = (r >> 2) * 16 + quad * 4 + (r & 3);
            numout[((size_t)bh * N_ + i0 + i) * 68 + dd] = numacc[r];
        }
    }
}

// ---------------------------------------------------------------------------
// Kernel 4: out[b,n,h*64+d] = (num0+num1)[bh,n,d] / (num0+num1)[bh,n,64]
// ---------------------------------------------------------------------------
__global__ __launch_bounds__(256) void finalize_kernel(const float* __restrict__ num0,
                                                       const float* __restrict__ num1,
                                                       float* __restrict__ out) {
    const int o = blockIdx.x * 256 + threadIdx.x;
    const int b = o / (N_ * C_);
    const int rem = o - b * (N_ * C_);
    const int n = rem >> 8;
    const int cc = rem & 255;
    const int h = cc >> 6, d = cc & 63;
    const size_t base = (((size_t)b * H_ + h) * N_ + n) * 68;
    const float nmr = num0[base + d]  + num1[base + d];
    const float dnr = num0[base + 64] + num1[base + 64];
    out[o] = nmr / dnr;
}

extern "C" void kernel_launch(void* const* d_in, const int* in_sizes, int n_in,
                              void* d_out, int out_size, void* d_ws, size_t ws_size,
                              hipStream_t stream) {
    const float* x = (const float*)d_in[0];
    const float* W = (const float*)d_in[1];
    float* ws    = (float*)d_ws;
    float* proj  = ws;                         // 5*TSZ f32
    float* ecd   = ws + 5 * TSZ;               // ESZ f32
    float* num1  = ecd + ESZ;                  // NWSLICE f32 (kt 3..5 partial)
    f16*   eabt  = (f16*)(num1 + NWSLICE);     // ESZ f16
    f16*   eef   = eabt + ESZ;                 // ESZ f16
    // num0 reuses proj slots 0-1 (a,b) -- dead after logits_kernel.
    // NWSLICE (208896) < 2*TSZ (393216), so it fits without touching v1/v2.
    float* num0  = ws;
    // total ws usage unchanged: ~14.2 MB

    proj_kernel<<<dim3(12, 20), 256, 0, stream>>>(x, W, proj);
    logits_kernel<<<dim3(6, 6, 24), 256, 0, stream>>>(proj, eabt, ecd, eef);
    triplet_mfma_kernel<<<dim3(6, 17, 16), 256, 0, stream>>>(
        eabt, ecd, eef, proj + 3 * TSZ, proj + 4 * TSZ, num0, num1);
    finalize_kernel<<<dim3(768), 256, 0, stream>>>(num0, num1, (float*)d_out);
}

// Round 4
// 259.758 us; speedup vs baseline: 2.9171x; 2.9171x over previous
//
#include <hip/hip_runtime.h>
#include <math.h>

#define B_  2
#define N_  384
#define C_  256
#define H_  4
#define D_  64
#define NBH (B_*H_)            // 8
#define TSZ (NBH*N_*D_)        // 196608 floats per projected tensor [bh][n][d]
#define ESZ (NBH*N_*N_)        // 1179648 elems per logit matrix [bh][i][j]
#define SCALE 0.125f           // D^-0.5
#define PIT 72                 // padded LDS pitch in f16 (144B) -> 2-way max bank alias

typedef _Float16 f16;
typedef f16  f16x8 __attribute__((ext_vector_type(8)));
typedef f16  f16x4 __attribute__((ext_vector_type(4)));
typedef float f32x4 __attribute__((ext_vector_type(4)));

// ---------------------------------------------------------------------------
// Kernel 1: projection (unchanged). proj[t][bh][n][d], t in {a,b,c,v1,v2}, f32.
// ---------------------------------------------------------------------------
__global__ __launch_bounds__(256) void proj_kernel(const float* __restrict__ x,
                                                   const float* __restrict__ W,
                                                   float* __restrict__ proj) {
    __shared__ float Xs[32][68];
    __shared__ float Ws[32][68];
    const int tid = threadIdx.x;
    const int tx = tid & 15, ty = tid >> 4;
    const int m0 = blockIdx.x * 64;
    const int c0 = blockIdx.y * 64;
    const int t  = c0 >> 8;
    const int wbase = ((t >= 3) ? (t + 3) : t) * 256;

    float acc[4][4] = {{0.f}};
    for (int k0 = 0; k0 < 256; k0 += 32) {
        __syncthreads();
#pragma unroll
        for (int l = 0; l < 8; ++l) {
            const int idx = l * 256 + tid;
            const int mi = idx >> 5, kk = idx & 31;
            Xs[kk][mi] = x[(m0 + mi) * 256 + k0 + kk];
            const int rem = (c0 + mi) & 255;
            Ws[kk][mi] = W[(wbase + rem) * 256 + k0 + kk];
        }
        __syncthreads();
#pragma unroll
        for (int kk = 0; kk < 32; ++kk) {
            const float4 xf = *(const float4*)&Xs[kk][ty * 4];
            const float4 wf = *(const float4*)&Ws[kk][tx * 4];
            const float xa[4] = {xf.x, xf.y, xf.z, xf.w};
            const float wa[4] = {wf.x, wf.y, wf.z, wf.w};
#pragma unroll
            for (int q = 0; q < 4; ++q)
#pragma unroll
                for (int p = 0; p < 4; ++p)
                    acc[q][p] += xa[q] * wa[p];
        }
    }
#pragma unroll
    for (int q = 0; q < 4; ++q) {
        const int r = m0 + ty * 4 + q;
        const int b = r / N_;
        const int n = r - b * N_;
#pragma unroll
        for (int p = 0; p < 4; ++p) {
            const int rem = (c0 + tx * 4 + p) & 255;
            const int h = rem >> 6, d = rem & 63;
            proj[t * TSZ + ((b * H_ + h) * N_ + n) * D_ + d] = acc[q][p];
        }
    }
}

// ---------------------------------------------------------------------------
// Kernel 2: exp-logit matrices, mixed-dtype outputs (unchanged).
// ---------------------------------------------------------------------------
__global__ __launch_bounds__(256) void logits_kernel(const float* __restrict__ proj,
                                                     f16* __restrict__ eabt16,
                                                     float* __restrict__ ecd,
                                                     f16* __restrict__ eef16) {
    __shared__ float Xs[32][68];
    __shared__ float Ys[32][68];
    const int tid = threadIdx.x;
    const int tx = tid & 15, ty = tid >> 4;
    const int i0 = blockIdx.x * 64, j0 = blockIdx.y * 64;
    const int q  = blockIdx.z >> 3;
    const int bh = blockIdx.z & 7;
    const int xt = q;
    const int yt = (q == 2) ? 0 : (q + 1);
    const float* Xp = proj + xt * TSZ + bh * N_ * D_;
    const float* Yp = proj + yt * TSZ + bh * N_ * D_;

    float acc[4][4] = {{0.f}};
    for (int k0 = 0; k0 < 64; k0 += 32) {
        __syncthreads();
#pragma unroll
        for (int l = 0; l < 8; ++l) {
            const int idx = l * 256 + tid;
            const int mi = idx >> 5, kk = idx & 31;
            Xs[kk][mi] = Xp[(i0 + mi) * 64 + k0 + kk];
            Ys[kk][mi] = Yp[(j0 + mi) * 64 + k0 + kk];
        }
        __syncthreads();
#pragma unroll
        for (int kk = 0; kk < 32; ++kk) {
            const float4 xf = *(const float4*)&Xs[kk][ty * 4];
            const float4 yf = *(const float4*)&Ys[kk][tx * 4];
            const float xa[4] = {xf.x, xf.y, xf.z, xf.w};
            const float ya[4] = {yf.x, yf.y, yf.z, yf.w};
#pragma unroll
            for (int qq = 0; qq < 4; ++qq)
#pragma unroll
                for (int p = 0; p < 4; ++p)
                    acc[qq][p] += xa[qq] * ya[p];
        }
    }
#pragma unroll
    for (int qq = 0; qq < 4; ++qq)
#pragma unroll
        for (int p = 0; p < 4; ++p) {
            const float e = expf(acc[qq][p] * SCALE);
            const int ii = i0 + ty * 4 + qq;
            const int jj = j0 + tx * 4 + p;
            if (q == 0)      eabt16[(size_t)bh * N_ * N_ + jj * N_ + ii] = (f16)e;
            else if (q == 1) ecd   [(size_t)bh * N_ * N_ + ii * N_ + jj] = e;
            else             eef16 [(size_t)bh * N_ * N_ + ii * N_ + jj] = (f16)e;
        }
}

// ---------------------------------------------------------------------------
// Kernel 3 (dominant), MFMA f16.
// Round-4 = round-0 data paths (all-LDS inner loop, 96-VGPR-friendly; rounds
// 1-3 proved global loads in the unrolled fold spill) + ONE structural change:
//  * es/abts double-buffered (ping-pong). One barrier per jt instead of two;
//    next tile's global loads issued BEFORE the compute phase (T14) so their
//    L2 latency hides under MFMA+fold instead of sitting between barriers.
//  * LDS 62464 -> 80896 B: still exactly 2 blocks/CU (163840/80896 = 2.02),
//    so occupancy is unchanged and stall time is the only thing attacked.
//  * kt-split reverted (tail-neutral at 2 blocks/CU, 2x prologue overhead).
//  * Hoisted zero4 C-in for the MFMA chains.
// ---------------------------------------------------------------------------
__global__ __launch_bounds__(256) void triplet_mfma_kernel(
        const f16*  __restrict__ eabt,   // [bh][j][i]
        const float* __restrict__ ecd,   // [bh][i][k]
        const f16*  __restrict__ eef,    // [bh][j][k]
        const float* __restrict__ v1,    // [bh][n][64]
        const float* __restrict__ v2,    // [bh][n][64]
        float* __restrict__ numout) {    // [bh][i][68]
    __shared__ __align__(16) unsigned char smem_raw[80896];
    f16*   us   = (f16*)smem_raw;                    // 4 * 64*PIT f16 = 36864 B
    f16*   es2  = (f16*)(smem_raw + 36864);          // 2 * 64*PIT f16 = 18432 B
    f16*   ab2  = (f16*)(smem_raw + 55296);          // 2 * 64*PIT f16 = 18432 B
    float* v1s  = (float*)(smem_raw + 73728);        // 384*4 f32      =  6144 B
    float* v2k  = (float*)(smem_raw + 79872);        // 4*64 f32       =  1024 B

    const int tid  = threadIdx.x;
    const int lane = tid & 63;
    const int w    = tid >> 6;        // wave id = d slot
    const int quad = lane >> 4;
    const int lr   = lane & 15;
    const int i0 = blockIdx.x * 64;
    const int dg = blockIdx.y;        // 0..16
    const int bh = blockIdx.z;
    const int dd = dg * 4 + w;        // 0..67 (>=64: denominator)

    const f16*   eabtb = eabt + (size_t)bh * N_ * N_;
    const float* ecdb  = ecd  + (size_t)bh * N_ * N_;
    const f16*   eefb  = eef  + (size_t)bh * N_ * N_;
    const float* v1b   = v1 + (size_t)bh * N_ * D_;
    const float* v2b   = v2 + (size_t)bh * N_ * D_;

    // stage v1 columns for the 4 d-slots: v1s[j*4 + c]
#pragma unroll
    for (int it = 0; it < 6; ++it) {
        const int id = it * 256 + tid;          // 0..1535
        const int j = id >> 2, c = id & 3;
        const int d2 = dg * 4 + c;
        v1s[id] = (d2 < 64) ? v1b[j * 64 + d2] : 1.0f;
    }
    __syncthreads();                  // v1s visible before first reads

    float numacc[16];
#pragma unroll
    for (int r = 0; r < 16; ++r) numacc[r] = 0.f;

    const f32x4 zero4 = {0.f, 0.f, 0.f, 0.f};

    // thread roles
    const int brow = tid >> 4;        // 0..15  (U-build)
    const int kcol = (tid & 15) * 4;  // 0..60
    const int srow = tid >> 3;        // 0..31  (es/abts staging)
    const int sblk = tid & 7;         // 0..7

    for (int kt = 0; kt < 6; ++kt) {
        const int k0 = kt * 64;
        // stage v2 chunk: v2k[c*64 + k]. Prior readers (last kt's U-build)
        // finished before last kt's "us ready" barrier.
        {
            const int c = tid >> 6, k = tid & 63;
            const int d2 = dg * 4 + c;
            v2k[c * 64 + k] = (d2 < 64) ? v2b[(k0 + k) * 64 + d2] : 1.0f;
        }
        __syncthreads();              // v2k ready
        // issue jt=0 tile loads now -- latency hides under the U-build VALU
        uint4 pe0 = *(const uint4*)(eefb  + srow        * N_ + k0 + sblk * 8);
        uint4 pe1 = *(const uint4*)(eefb  + (32 + srow) * N_ + k0 + sblk * 8);
        uint4 pa0 = *(const uint4*)(eabtb + srow        * N_ + i0 + sblk * 8);
        uint4 pa1 = *(const uint4*)(eabtb + (32 + srow) * N_ + i0 + sblk * 8);
        // build U16[d][64i][PIT k] = f16(eCD * v2col)
#pragma unroll
        for (int it = 0; it < 4; ++it) {
            const int row = it * 16 + brow;
            const float4 c4 = *(const float4*)&ecdb[(i0 + row) * N_ + k0 + kcol];
#pragma unroll
            for (int d = 0; d < 4; ++d) {
                const float4 w4 = *(const float4*)&v2k[d * 64 + kcol];
                union { f16 h[4]; unsigned long long u; } pk;
                pk.h[0] = (f16)(c4.x * w4.x);
                pk.h[1] = (f16)(c4.y * w4.y);
                pk.h[2] = (f16)(c4.z * w4.z);
                pk.h[3] = (f16)(c4.w * w4.w);
                *(unsigned long long*)(us + d * 64 * PIT + row * PIT + kcol) = pk.u;
            }
        }
        // write jt=0 tile into buffer 0 (waits vmcnt for pe*/pa* implicitly)
        *(uint4*)(es2 + srow * PIT + sblk * 8)        = pe0;
        *(uint4*)(es2 + (32 + srow) * PIT + sblk * 8) = pe1;
        *(uint4*)(ab2 + srow * PIT + sblk * 8)        = pa0;
        *(uint4*)(ab2 + (32 + srow) * PIT + sblk * 8) = pa1;
        __syncthreads();              // us + buf0 ready
        // A-frags for this wave's d, all 4 i-subtiles x 2 k-halves
        f16x8 af[4][2];
#pragma unroll
        for (int isub = 0; isub < 4; ++isub)
#pragma unroll
            for (int ks = 0; ks < 2; ++ks)
                af[isub][ks] = *(const f16x8*)(us + w * 64 * PIT +
                                               (isub * 16 + lr) * PIT + (ks * 4 + quad) * 8);

        for (int jt = 0; jt < 6; ++jt) {
            const int j0 = jt * 64;
            const int p  = jt & 1;
            const f16* esp = es2 + p * 64 * PIT;
            const f16* abp = ab2 + p * 64 * PIT;
            // T14: issue NEXT tile's global loads before compute
            uint4 qe0, qe1, qa0, qa1;
            if (jt < 5) {
                const int jn = j0 + 64;
                qe0 = *(const uint4*)(eefb  + (jn + srow)      * N_ + k0 + sblk * 8);
                qe1 = *(const uint4*)(eefb  + (jn + 32 + srow) * N_ + k0 + sblk * 8);
                qa0 = *(const uint4*)(eabtb + (jn + srow)      * N_ + i0 + sblk * 8);
                qa1 = *(const uint4*)(eabtb + (jn + 32 + srow) * N_ + i0 + sblk * 8);
            }
            // compute from buffer p (MFMA + immediate fold of partial R)
#pragma unroll
            for (int js = 0; js < 4; ++js) {
                const f16x8 bf0 = *(const f16x8*)(esp + (js * 16 + lr) * PIT + quad * 8);
                const f16x8 bf1 = *(const f16x8*)(esp + (js * 16 + lr) * PIT + (4 + quad) * 8);
                const float v1v = v1s[(j0 + js * 16 + lr) * 4 + w];
#pragma unroll
                for (int isub = 0; isub < 4; ++isub) {
                    f32x4 t;
                    t = __builtin_amdgcn_mfma_f32_16x16x32_f16(af[isub][0], bf0, zero4, 0, 0, 0);
                    t = __builtin_amdgcn_mfma_f32_16x16x32_f16(af[isub][1], bf1, t, 0, 0, 0);
                    const f16x4 ab = *(const f16x4*)(abp + (js * 16 + lr) * PIT +
                                                     isub * 16 + quad * 4);
#pragma unroll
                    for (int q = 0; q < 4; ++q)
                        numacc[isub * 4 + q] += (float)ab[q] * (v1v * t[q]);
                }
            }
            // write next tile into buffer p^1 (its readers finished at the
            // barrier that ended jt-1; concurrent readers are on buffer p)
            if (jt < 5) {
                f16* esn = es2 + (p ^ 1) * 64 * PIT;
                f16* abn = ab2 + (p ^ 1) * 64 * PIT;
                *(uint4*)(esn + srow * PIT + sblk * 8)        = qe0;
                *(uint4*)(esn + (32 + srow) * PIT + sblk * 8) = qe1;
                *(uint4*)(abn + srow * PIT + sblk * 8)        = qa0;
                *(uint4*)(abn + (32 + srow) * PIT + sblk * 8) = qa1;
            }
            __syncthreads();          // one barrier per jt
        }
    }
    // reduce the j-residues (low 4 lane bits) and write
#pragma unroll
    for (int r = 0; r < 16; ++r) {
        float v = numacc[r];
        v += __shfl_xor(v, 1);
        v += __shfl_xor(v, 2);
        v += __shfl_xor(v, 4);
        v += __shfl_xor(v, 8);
        numacc[r] = v;
    }
    if (lr == 0) {
#pragma unroll
        for (int r = 0; r < 16; ++r) {
            const int i = (r >> 2) * 16 + quad * 4 + (r & 3);
            numout[((size_t)bh * N_ + i0 + i) * 68 + dd] = numacc[r];
        }
    }
}

// ---------------------------------------------------------------------------
// Kernel 4: out[b,n,h*64+d] = num[bh,n,d] / num[bh,n,64]
// ---------------------------------------------------------------------------
__global__ __launch_bounds__(256) void finalize_kernel(const float* __restrict__ numw,
                                                       float* __restrict__ out) {
    const int o = blockIdx.x * 256 + threadIdx.x;
    const int b = o / (N_ * C_);
    const int rem = o - b * (N_ * C_);
    const int n = rem >> 8;
    const int cc = rem & 255;
    const int h = cc >> 6, d = cc & 63;
    const float* base = numw + (((size_t)b * H_ + h) * N_ + n) * 68;
    out[o] = base[d] / base[64];
}

extern "C" void kernel_launch(void* const* d_in, const int* in_sizes, int n_in,
                              void* d_out, int out_size, void* d_ws, size_t ws_size,
                              hipStream_t stream) {
    const float* x = (const float*)d_in[0];
    const float* W = (const float*)d_in[1];
    float* ws    = (float*)d_ws;
    float* proj  = ws;                         // 5*TSZ f32
    float* ecd   = ws + 5 * TSZ;               // ESZ f32
    float* numw  = ecd + ESZ;                  // 8*384*68 f32 = 208896
    f16*   eabt  = (f16*)(numw + NBH * N_ * 68);  // ESZ f16
    f16*   eef   = eabt + ESZ;                 // ESZ f16
    // total ~14.2 MB of d_ws

    proj_kernel<<<dim3(12, 20), 256, 0, stream>>>(x, W, proj);
    logits_kernel<<<dim3(6, 6, 24), 256, 0, stream>>>(proj, eabt, ecd, eef);
    triplet_mfma_kernel<<<dim3(6, 17, 8), 256, 0, stream>>>(
        eabt, ecd, eef, proj + 3 * TSZ, proj + 4 * TSZ, numw);
    finalize_kernel<<<dim3(768), 256, 0, stream>>>(numw, (float*)d_out);
}